// Round 1
// baseline (78.795 us; speedup 1.0000x reference)
//
#include <hip/hip_runtime.h>
#include <math.h>

#define BB 4
#define NN 16384
#define CC 128
#define MM 128
#define SS 512
#define OUT_ROW 131   // 3 coords + 128 features

// One block per (b, m) box. 512 threads = 8 waves.
// Phase 1: stable-order collection of in-box point indices (first SS) + exact count.
// Phase 2: wave-per-row gather of [xyz | feats] into output.
__global__ __launch_bounds__(512) void roipool3d_kernel(
    const float* __restrict__ points,   // (B, N, 3)
    const float* __restrict__ feats,    // (B, N, C)
    const float* __restrict__ boxes,    // (B, M, 7)
    float* __restrict__ out_feat,       // (B, M, S, 131)
    float* __restrict__ out_flag)       // (B, M) written as float 0/1
{
    const int bm   = blockIdx.x;           // 0..511
    const int b    = bm >> 7;              // / MM
    const int m    = bm & (MM - 1);
    const int tid  = threadIdx.x;
    const int lane = tid & 63;
    const int wave = tid >> 6;             // 0..7

    __shared__ int s_idx[SS];
    __shared__ int s_wcnt[8];
    __shared__ int s_total;

    // ---- box params, enlarged: cz -= 0.5, d* += 1.0 (POOL_EXTRA_WIDTH = 1) ----
    const float* bx = boxes + (size_t)(b * MM + m) * 7;
    const float cx  = bx[0];
    const float cy  = bx[1];
    const float cz  = __fadd_rn(bx[2], -0.5f);
    const float dx  = __fadd_rn(bx[3], 1.0f);
    const float dy  = __fadd_rn(bx[4], 1.0f);
    const float dz  = __fadd_rn(bx[5], 1.0f);
    const float yaw = bx[6];
    // correctly-rounded f32 cos/sin via double to track the reference closely
    const float cosa = (float)cos((double)yaw);
    const float sina = (float)sin((double)yaw);
    const float hx = __fmul_rn(dx, 0.5f);
    const float hy = __fmul_rn(dy, 0.5f);
    const float hz = __fmul_rn(dz, 0.5f);
    const float zc = __fadd_rn(cz, hz);    // cz + dz*0.5

    if (tid == 0) s_total = 0;
    __syncthreads();

    const float* pbase = points + (size_t)b * NN * 3;

    // ---- phase 1: scan all N points in ascending order, chunk = 512 ----
    for (int base = 0; base < NN; base += 512) {
        const int i = base + tid;
        const float px = pbase[i * 3 + 0];
        const float py = pbase[i * 3 + 1];
        const float pz = pbase[i * 3 + 2];
        const float sx = __fadd_rn(px, -cx);
        const float sy = __fadd_rn(py, -cy);
        // unfused mul/add to mimic plain f32 arithmetic of the reference
        const float lx = __fadd_rn(__fmul_rn(sx, cosa), __fmul_rn(sy, sina));
        const float ly = __fadd_rn(__fmul_rn(-sx, sina), __fmul_rn(sy, cosa));
        const bool in_box = (fabsf(lx) < hx) & (fabsf(ly) < hy) &
                            (fabsf(__fadd_rn(pz, -zc)) <= hz);

        const unsigned long long mask = __ballot(in_box);
        if (lane == 0) s_wcnt[wave] = __popcll(mask);
        __syncthreads();

        const int prev = s_total;
        int woff = 0;
        #pragma unroll
        for (int w = 0; w < 8; ++w) woff += (w < wave) ? s_wcnt[w] : 0;
        const int pos = prev + woff +
                        __popcll(mask & ((1ull << lane) - 1ull));
        if (in_box && pos < SS) s_idx[pos] = i;
        __syncthreads();

        if (tid == 0) {
            int t = 0;
            #pragma unroll
            for (int w = 0; w < 8; ++w) t += s_wcnt[w];
            s_total = prev + t;
        }
        __syncthreads();
    }

    const int cnt = s_total;
    float* obase = out_feat + (size_t)bm * SS * OUT_ROW;

    // ---- phase 2: gather ----
    if (cnt == 0) {
        for (int e = tid; e < SS * OUT_ROW; e += 512) obase[e] = 0.0f;
        if (tid == 0) out_flag[bm] = 1.0f;
        return;
    }
    if (tid == 0) out_flag[bm] = 0.0f;

    const float* fbase = feats + (size_t)b * NN * CC;

    // one wave per output row
    for (int row = wave; row < SS; row += 8) {
        const int j  = (row < cnt) ? row : (row % cnt);
        const int pi = s_idx[j];
        float* orow = obase + (size_t)row * OUT_ROW;
        if (lane < 3) orow[lane] = pbase[pi * 3 + lane];
        const float* frow = fbase + (size_t)pi * CC;
        orow[3 + lane]      = frow[lane];
        orow[3 + 64 + lane] = frow[64 + lane];
    }
}

extern "C" void kernel_launch(void* const* d_in, const int* in_sizes, int n_in,
                              void* d_out, int out_size, void* d_ws, size_t ws_size,
                              hipStream_t stream) {
    const float* points = (const float*)d_in[0];
    const float* feats  = (const float*)d_in[1];
    const float* boxes  = (const float*)d_in[2];
    float* out_feat = (float*)d_out;
    float* out_flag = (float*)d_out + (size_t)BB * MM * SS * OUT_ROW;

    roipool3d_kernel<<<BB * MM, 512, 0, stream>>>(points, feats, boxes,
                                                  out_feat, out_flag);
}

// Round 2
// 61.447 us; speedup vs baseline: 1.2823x; 1.2823x over previous
//
#include <hip/hip_runtime.h>
#include <math.h>

#define BB 4
#define NN 16384
#define CC 128
#define MM 128
#define SS 512
#define OUT_ROW 131   // 3 coords + 128 features
#define NSEG 256      // 16384 / 64 segments per box
#define G 8           // row-groups per box in gather kernel
#define RPG (SS / G)  // 64 rows per group

// ---------------- K1: per-box stable in-box index selection ----------------
// 512 blocks (one per box) x 512 threads (8 waves).
// Pass A (no barriers): each wave ballots 32 contiguous 64-point segments,
//   storing masks to LDS.
// Pass B: shfl-based prefix scan of the 256 segment popcounts.
// Pass C: parallel bit-iteration writes first SS in-box indices to ws.
__global__ __launch_bounds__(512) void k1_select(
    const float* __restrict__ points,   // (B, N, 3)
    const float* __restrict__ boxes,    // (B, M, 7)
    int* __restrict__ ws_idx,           // (B*M, SS)
    int* __restrict__ ws_cnt,           // (B*M)
    float* __restrict__ out_flag)       // (B*M) as float 0/1
{
    const int bm   = blockIdx.x;
    const int b    = bm >> 7;
    const int m    = bm & (MM - 1);
    const int tid  = threadIdx.x;
    const int lane = tid & 63;
    const int wave = tid >> 6;

    __shared__ unsigned long long s_mask[NSEG];
    __shared__ int s_wsum[4];

    // box params, enlarged: cz -= 0.5, d* += 1.0
    const float* bx = boxes + (size_t)(b * MM + m) * 7;
    const float cx  = bx[0];
    const float cy  = bx[1];
    const float cz  = __fadd_rn(bx[2], -0.5f);
    const float hx  = __fmul_rn(__fadd_rn(bx[3], 1.0f), 0.5f);
    const float hy  = __fmul_rn(__fadd_rn(bx[4], 1.0f), 0.5f);
    const float hz  = __fmul_rn(__fadd_rn(bx[5], 1.0f), 0.5f);
    const float yaw = bx[6];
    const float cosa = (float)cos((double)yaw);
    const float sina = (float)sin((double)yaw);
    const float zc   = __fadd_rn(cz, hz);

    const float* pbase = points + (size_t)b * NN * 3;

    // ---- Pass A: wave w handles segments [w*32, w*32+32) ----
    #pragma unroll 4
    for (int k = 0; k < 32; ++k) {
        const int s = wave * 32 + k;
        const int i = s * 64 + lane;
        const float px = pbase[i * 3 + 0];
        const float py = pbase[i * 3 + 1];
        const float pz = pbase[i * 3 + 2];
        const float sx = __fadd_rn(px, -cx);
        const float sy = __fadd_rn(py, -cy);
        const float lx = __fadd_rn(__fmul_rn(sx, cosa), __fmul_rn(sy, sina));
        const float ly = __fadd_rn(__fmul_rn(-sx, sina), __fmul_rn(sy, cosa));
        const bool in_box = (fabsf(lx) < hx) & (fabsf(ly) < hy) &
                            (fabsf(__fadd_rn(pz, -zc)) <= hz);
        const unsigned long long mask = __ballot(in_box);
        if (lane == 0) s_mask[s] = mask;
    }
    __syncthreads();

    // ---- Pass B: prefix scan over 256 segment counts (threads 0..255) ----
    unsigned long long mymask = 0ull;
    int c = 0;
    if (tid < NSEG) {
        mymask = s_mask[tid];
        c = __popcll(mymask);
    }
    int inc = c;
    #pragma unroll
    for (int d = 1; d < 64; d <<= 1) {
        int v = __shfl_up(inc, d);
        if (lane >= d) inc += v;
    }
    if (tid < NSEG && lane == 63) s_wsum[wave] = inc;
    __syncthreads();

    int woff = 0, total = 0;
    #pragma unroll
    for (int w = 0; w < 4; ++w) {
        const int v = s_wsum[w];
        if (w < wave) woff += v;
        total += v;
    }

    // ---- Pass C: emit indices (stable ascending order), first SS only ----
    if (tid < NSEG) {
        int base = woff + inc - c;          // exclusive prefix
        if (base < SS) {
            unsigned long long mk = mymask;
            int* dst = ws_idx + (size_t)bm * SS;
            while (mk) {
                const int bit = __ffsll(mk) - 1;
                mk &= mk - 1;
                dst[base] = tid * 64 + bit;
                if (++base >= SS) break;
            }
        }
    }
    if (tid == 0) {
        ws_cnt[bm] = total;
        out_flag[bm] = (total == 0) ? 1.0f : 0.0f;
    }
}

// ---------------- K2: gather + stream-write ----------------
// 4096 blocks (box x row-group) x 256 threads (4 waves).
__global__ __launch_bounds__(256) void k2_gather(
    const float* __restrict__ points,
    const float* __restrict__ feats,    // (B, N, C)
    const int* __restrict__ ws_idx,
    const int* __restrict__ ws_cnt,
    float* __restrict__ out_feat)       // (B, M, S, 131)
{
    const int blk = blockIdx.x;
    const int bm  = blk >> 3;
    const int g   = blk & (G - 1);
    const int row0 = g * RPG;
    const int tid  = threadIdx.x;

    const int cnt = ws_cnt[bm];
    float* obase = out_feat + (size_t)bm * SS * OUT_ROW;

    if (cnt == 0) {
        float* o = obase + (size_t)row0 * OUT_ROW;
        for (int e = tid; e < RPG * OUT_ROW; e += 256) o[e] = 0.0f;
        return;
    }

    __shared__ int s_pi[RPG];
    if (tid < RPG) {
        const int row = row0 + tid;
        const int j = (row < cnt) ? row : (row % cnt);
        s_pi[tid] = ws_idx[(size_t)bm * SS + j];
    }
    __syncthreads();

    const int lane = tid & 63;
    const int wave = tid >> 6;
    const int b = bm >> 7;
    const float* pbase = points + (size_t)b * NN * 3;
    const float* fbase = feats + (size_t)b * NN * CC;

    #pragma unroll 4
    for (int r = wave; r < RPG; r += 4) {
        const int pi = s_pi[r];
        float* orow = obase + (size_t)(row0 + r) * OUT_ROW;
        if (lane < 3) orow[lane] = pbase[pi * 3 + lane];
        const float* frow = fbase + (size_t)pi * CC;
        orow[3 + lane]      = frow[lane];
        orow[67 + lane]     = frow[64 + lane];
    }
}

extern "C" void kernel_launch(void* const* d_in, const int* in_sizes, int n_in,
                              void* d_out, int out_size, void* d_ws, size_t ws_size,
                              hipStream_t stream) {
    const float* points = (const float*)d_in[0];
    const float* feats  = (const float*)d_in[1];
    const float* boxes  = (const float*)d_in[2];
    float* out_feat = (float*)d_out;
    float* out_flag = (float*)d_out + (size_t)BB * MM * SS * OUT_ROW;

    int* ws_idx = (int*)d_ws;                       // 512*512 ints = 1 MB
    int* ws_cnt = ws_idx + (size_t)BB * MM * SS;    // 512 ints

    k1_select<<<BB * MM, 512, 0, stream>>>(points, boxes, ws_idx, ws_cnt, out_flag);
    k2_gather<<<BB * MM * G, 256, 0, stream>>>(points, feats, ws_idx, ws_cnt, out_feat);
}